// Round 9
// baseline (136.461 us; speedup 1.0000x reference)
//
#include <hip/hip_runtime.h>

#define B_ 4
#define Q_ 512
#define K_ 512
#define F_ 32
#define H1_ 256
#define H2_ 64
#define HV_ 64

typedef unsigned short u16;
typedef unsigned int u32;

typedef float f32x4 __attribute__((ext_vector_type(4)));
typedef short short8 __attribute__((ext_vector_type(8)));
typedef __bf16 bfv8 __attribute__((ext_vector_type(8)));
union FRG { short8 s; bfv8 h; u32 u[4]; };

// ---- workspace layout (float units from ws base) ----
#define OFF_QS   0
#define OFF_KS   65536
#define OFF_VS   131072
#define OFF_VN   196608
#define OFF_QSS  196736
#define OFF_KSS  200832
#define OFF_QST  204928
#define OFF_KST  206976
#define OFF_W1   209024
#define OFF_B1   234880
#define OFF_W2   235136   /* u32 region: 8192 u32 packed B-fragments */
#define OFF_B2   243328
#define OFF_W3   243392
#define OFF_B3   243456
#define OFF_WV   243460
#define OFF_BV   245508
#define OFF_VL   245572   /* 4 ints */
#define OFF_AQ   262144
#define OFF_AK   786432   /* row-major Ak[b][k][d], 524288 floats */
#define OFF_VP   1310720

__device__ __forceinline__ float bf2f(u16 u) {
    union { u32 u; float f; } c; c.u = ((u32)u) << 16; return c.f;
}
__device__ __forceinline__ u16 f2bf(float f) {
    union { float f; u32 u; } c; c.f = f;
    u32 u = c.u;
    return (u16)((u + 0x7FFFu + ((u >> 16) & 1u)) >> 16);
}
// jax.nn.gelu(approximate=True) == x - x/(1+exp2(x*(K + Kc*x^2)))
__device__ __forceinline__ float gelu_t(float x) {
    const float Kb = 2.3022082f;     // 2*sqrt(2/pi)*log2(e)
    const float Kc = 0.10294324f;    // Kb*0.044715
    float y = x * __builtin_fmaf(Kc, x * x, Kb);
    float e = __builtin_amdgcn_exp2f(y);
    return x - x * __builtin_amdgcn_rcpf(e + 1.0f);  // exact at both tails
}

// ---------------- convert: canonicalize inputs to f32; pack W2 into MFMA B-fragments --------
__global__ __launch_bounds__(256) void convert_kernel(
    const void* s0, const void* s1, const void* s2, const void* s3,
    const void* s4, const void* s5, const void* s6, const void* s7,
    const void* s8, const void* s9, const void* s10, const void* s11,
    const void* s12, const void* s13, const void* s14, const void* s15,
    const void* s16, float* wsf)
{
    int blk = blockIdx.x, t = threadIdx.x;
    // qs_t is all ones: f32 -> 0x3F800000, bf16 pair -> 0x3F803F80
    int bf16m = (((const u32*)s6)[0] != 0x3F800000u);

    if (blk == 963) {           // valid_lens (int32 or int64 hedge)
        if (t < 4) {
            const int* vi = (const int*)s16;
            int is64 = (vi[1] == 0);
            ((int*)(wsf + OFF_VL))[t] = vi[is64 ? 2 * t : t];
        }
        return;
    }
    if (blk >= 919 && blk < 951) {   // W2 -> packed B-fragments W2F[ks][n][lane][r]
        int idx = (blk - 919) * 256 + t;           // 0..8191
        int r  = idx & 3;
        int l  = (idx >> 2) & 63;
        int n  = (idx >> 8) & 3;
        int ks = idx >> 10;
        int k0  = ks * 32 + (l >> 4) * 8 + 2 * r;
        int col = n * 16 + (l & 15);
        u16 lo, hi;
        if (bf16m) {
            lo = ((const u16*)s10)[k0 * H2_ + col];
            hi = ((const u16*)s10)[(k0 + 1) * H2_ + col];
        } else {
            lo = f2bf(((const float*)s10)[k0 * H2_ + col]);
            hi = f2bf(((const float*)s10)[(k0 + 1) * H2_ + col]);
        }
        ((u32*)(wsf + OFF_W2))[idx] = (u32)lo | ((u32)hi << 16);
        return;
    }
    const void* src; int n, dst, b0;
    if      (blk < 256) { src = s0;  n = 65536; dst = OFF_QS;  b0 = 0;   }
    else if (blk < 512) { src = s1;  n = 65536; dst = OFF_KS;  b0 = 256; }
    else if (blk < 768) { src = s2;  n = 65536; dst = OFF_VS;  b0 = 512; }
    else if (blk < 769) { src = s3;  n = 128;   dst = OFF_VN;  b0 = 768; }
    else if (blk < 785) { src = s4;  n = 4096;  dst = OFF_QSS; b0 = 769; }
    else if (blk < 801) { src = s5;  n = 4096;  dst = OFF_KSS; b0 = 785; }
    else if (blk < 809) { src = s6;  n = 2048;  dst = OFF_QST; b0 = 801; }
    else if (blk < 817) { src = s7;  n = 2048;  dst = OFF_KST; b0 = 809; }
    else if (blk < 918) { src = s8;  n = 25856; dst = OFF_W1;  b0 = 817; }
    else if (blk < 919) { src = s9;  n = 256;   dst = OFF_B1;  b0 = 918; }
    else if (blk < 952) { src = s11; n = 64;    dst = OFF_B2;  b0 = 951; }
    else if (blk < 953) { src = s12; n = 64;    dst = OFF_W3;  b0 = 952; }
    else if (blk < 954) { src = s13; n = 1;     dst = OFF_B3;  b0 = 953; }
    else if (blk < 962) { src = s14; n = 2048;  dst = OFF_WV;  b0 = 954; }
    else                { src = s15; n = 64;    dst = OFF_BV;  b0 = 962; }
    int idx = (blk - b0) * 256 + t;
    if (idx < n)
        (wsf + dst)[idx] = bf16m ? bf2f(((const u16*)src)[idx]) : ((const float*)src)[idx];
}

// ---------------- prep: Aq, Ak (row-major), vproj — all f32 ----------------
__global__ __launch_bounds__(256) void prep_kernel(
    const float* __restrict__ qs, const float* __restrict__ ks, const float* __restrict__ vs,
    const float* __restrict__ vnode, const float* __restrict__ qs_s, const float* __restrict__ ks_s,
    const float* __restrict__ qs_t, const float* __restrict__ ks_t,
    const float* __restrict__ W1, const float* __restrict__ b1,
    const float* __restrict__ Wv, const float* __restrict__ bv,
    float* __restrict__ Aq, float* __restrict__ Ak, float* __restrict__ vproj)
{
    int blk = blockIdx.x;
    int t = threadIdx.x;
    if (blk < 2048) {                       // Aq row per (b,q)
        int b = blk >> 9, q = blk & 511, d = t;
        float acc = b1[d];
        const float* qrow = qs + (b * Q_ + q) * F_;
        #pragma unroll
        for (int f = 0; f < F_; ++f)
            acc = __builtin_fmaf(qrow[f], W1[f * H1_ + d], acc);
        const float* vn = vnode + b * 32;
        #pragma unroll
        for (int f = 0; f < 32; ++f)
            acc = __builtin_fmaf(vn[f], W1[(64 + f) * H1_ + d], acc);
        float q0 = qs_s[(b * Q_ + q) * 2 + 0];
        float q1 = qs_s[(b * Q_ + q) * 2 + 1];
        float qt = qs_t[b * Q_ + q];
        acc = __builtin_fmaf(q0, W1[96 * H1_ + d], acc);
        acc = __builtin_fmaf(q1, W1[97 * H1_ + d], acc);
        acc = __builtin_fmaf(qt, W1[100 * H1_ + d], acc);
        Aq[blk * H1_ + d] = acc;
    } else if (blk < 4096) {                // Ak[b][k][d]
        int rk = blk - 2048;
        int b = rk >> 9, k = rk & 511, d = t;
        float acc = 0.f;
        const float* krow = ks + (b * K_ + k) * F_;
        #pragma unroll
        for (int f = 0; f < F_; ++f)
            acc = __builtin_fmaf(krow[f], W1[(32 + f) * H1_ + d], acc);
        float k0 = ks_s[(b * K_ + k) * 2 + 0];
        float k1 = ks_s[(b * K_ + k) * 2 + 1];
        float kt = ks_t[b * K_ + k];
        acc = __builtin_fmaf(-k0, W1[96 * H1_ + d], acc);
        acc = __builtin_fmaf(-k1, W1[97 * H1_ + d], acc);
        acc = __builtin_fmaf(-kt, W1[100 * H1_ + d], acc);
        Ak[(b * K_ + k) * H1_ + d] = acc;   // row-major: lane reads 8 consecutive d
    } else {                                // vproj[(b,k),h]
        int idx = (blk - 4096) * 256 + t;
        int h = idx & 63;
        int k = (idx >> 6) & 511;
        int b = idx >> 15;
        float acc = bv[h];
        const float* vrow = vs + (b * K_ + k) * F_;
        #pragma unroll
        for (int f = 0; f < F_; ++f)
            acc = __builtin_fmaf(vrow[f], Wv[f * HV_ + h], acc);
        vproj[idx] = acc;
    }
}

// ---------------- fused: 2 q's per 8-wave block; MFMA MLP + softmax + attn + ctx ------
// Waves stride 16-row tiles by 8 (load-balanced for any VL); Ak/W2F/vproj loads
// amortized across the q-pair; two independent MFMA chains give VALU/MFMA overlap.
__global__ __launch_bounds__(512, 8) void fused_kernel(
    const float* __restrict__ qs_s, const float* __restrict__ ks_s,
    const float* __restrict__ qs_t, const float* __restrict__ ks_t,
    const float* __restrict__ W1, const u32* __restrict__ W2F,
    const float* __restrict__ b2, const float* __restrict__ W3, const float* __restrict__ b3,
    const int* __restrict__ vl, const float* __restrict__ Aq, const float* __restrict__ Ak,
    const float* __restrict__ vproj, const void* __restrict__ qs_t_src, void* __restrict__ d_out)
{
    __shared__ __align__(16) float sAq[2][H1_];
    __shared__ __align__(16) float sw98[H1_], sw99[H1_];
    __shared__ float sScore[2][K_];
    __shared__ float sE[2][K_];
    __shared__ float sRed[2][12];
    __shared__ float sPart[2][8][HV_];

    int q0 = blockIdx.x * 2, b = blockIdx.y, t = threadIdx.x;
    int lane = t & 63, w = t >> 6;         // 8 waves
    int VL = vl[b];
    int nT = (VL + 15) >> 4;               // m-tiles of 16 rows covering [0, VL)

    if (t < H1_) {
        sAq[0][t] = Aq[(b * Q_ + q0) * H1_ + t];
        sAq[1][t] = Aq[(b * Q_ + q0 + 1) * H1_ + t];
        sw98[t] = W1[98 * H1_ + t];
        sw99[t] = W1[99 * H1_ + t];
    }
    __syncthreads();

    float qx0[2], qx1[2], qtv[2];
    #pragma unroll
    for (int qq = 0; qq < 2; ++qq) {
        qx0[qq] = qs_s[(b * Q_ + q0 + qq) * 2 + 0];
        qx1[qq] = qs_s[(b * Q_ + q0 + qq) * 2 + 1];
        qtv[qq] = qs_t[b * Q_ + q0 + qq];
    }

    float b2c[4], w3c[4];
    #pragma unroll
    for (int n = 0; n < 4; ++n) {
        int col = n * 16 + (lane & 15);
        b2c[n] = b2[col];
        w3c[n] = W3[col];
    }
    float b3v = b3[0];
    const float* Ak_b = Ak + (size_t)b * K_ * H1_;
    int lgrp = (lane >> 4) * 8;

    for (int tile = w; tile < nT; tile += 8) {     // wave-uniform strided tiles
        int row = tile * 16 + (lane & 15);
        float c0 = ks_s[(b * K_ + row) * 2 + 0];
        float c1 = ks_s[(b * K_ + row) * 2 + 1];
        float ktv = ks_t[b * K_ + row];
        float dsq[2], dist[2], okf[2];
        #pragma unroll
        for (int qq = 0; qq < 2; ++qq) {
            float d0 = qx0[qq] - c0, d1 = qx1[qq] - c1;
            dsq[qq]  = __builtin_fmaf(d0, d0, d1 * d1);
            dist[qq] = sqrtf(dsq[qq]);
            okf[qq] = (row < VL && (qtv[qq] - ktv) >= 0.f && dist[qq] <= 1e30f) ? 1.f : 0.f;
        }

        f32x4 acc[2][4];
        #pragma unroll
        for (int qq = 0; qq < 2; ++qq)
            #pragma unroll
            for (int n = 0; n < 4; ++n) acc[qq][n] = (f32x4){0.f, 0.f, 0.f, 0.f};

        const float* akrow = Ak_b + row * H1_;
        #pragma unroll 2
        for (int ks = 0; ks < 8; ++ks) {
            int dbase = ks * 32 + lgrp;
            f32x4 w98a = *(const f32x4*)&sw98[dbase];
            f32x4 w98b = *(const f32x4*)&sw98[dbase + 4];
            f32x4 w99a = *(const f32x4*)&sw99[dbase];
            f32x4 w99b = *(const f32x4*)&sw99[dbase + 4];
            f32x4 ak0 = *(const f32x4*)(akrow + dbase);
            f32x4 ak1 = *(const f32x4*)(akrow + dbase + 4);
            short8 bf[4];
            #pragma unroll
            for (int n = 0; n < 4; ++n)
                bf[n] = *(const short8*)&W2F[((ks * 4 + n) * 64 + lane) * 4];  // L1-hot
            FRG fa[2];
            #pragma unroll
            for (int qq = 0; qq < 2; ++qq) {
                f32x4 aqa = *(const f32x4*)&sAq[qq][dbase];
                f32x4 aqb = *(const f32x4*)&sAq[qq][dbase + 4];
                #pragma unroll
                for (int j = 0; j < 4; ++j) {
                    float pre = ak0[j] + __builtin_fmaf(dist[qq], w98a[j],
                               __builtin_fmaf(dsq[qq], w99a[j], aqa[j]));
                    fa[qq].h[j] = (__bf16)gelu_t(pre);
                }
                #pragma unroll
                for (int j = 0; j < 4; ++j) {
                    float pre = ak1[j] + __builtin_fmaf(dist[qq], w98b[j],
                               __builtin_fmaf(dsq[qq], w99b[j], aqb[j]));
                    fa[qq].h[4 + j] = (__bf16)gelu_t(pre);
                }
            }
            #pragma unroll
            for (int n = 0; n < 4; ++n) {
                acc[0][n] = __builtin_amdgcn_mfma_f32_16x16x32_bf16(fa[0].s, bf[n], acc[0][n], 0, 0, 0);
                acc[1][n] = __builtin_amdgcn_mfma_f32_16x16x32_bf16(fa[1].s, bf[n], acc[1][n], 0, 0, 0);
            }
        }

        // ---- layer-3 for this tile, both q's ----
        #pragma unroll
        for (int qq = 0; qq < 2; ++qq) {
            float s0 = 0.f, s1 = 0.f, s2 = 0.f, s3 = 0.f;
            #pragma unroll
            for (int n = 0; n < 4; ++n) {
                f32x4 a = acc[qq][n];
                s0 = __builtin_fmaf(gelu_t(a.x + b2c[n]), w3c[n], s0);
                s1 = __builtin_fmaf(gelu_t(a.y + b2c[n]), w3c[n], s1);
                s2 = __builtin_fmaf(gelu_t(a.z + b2c[n]), w3c[n], s2);
                s3 = __builtin_fmaf(gelu_t(a.w + b2c[n]), w3c[n], s3);
            }
            #pragma unroll
            for (int off = 1; off < 16; off <<= 1) {
                s0 += __shfl_xor(s0, off);
                s1 += __shfl_xor(s1, off);
                s2 += __shfl_xor(s2, off);
                s3 += __shfl_xor(s3, off);
            }
            int g = lane >> 4;
            float ok0 = __shfl(okf[qq], g * 4 + 0);
            float ok1 = __shfl(okf[qq], g * 4 + 1);
            float ok2 = __shfl(okf[qq], g * 4 + 2);
            float ok3 = __shfl(okf[qq], g * 4 + 3);
            if ((lane & 15) == 0) {
                int r0 = tile * 16 + g * 4;
                const float NEG = -__builtin_inff();
                sScore[qq][r0 + 0] = (ok0 != 0.f) ? s0 + b3v : NEG;
                sScore[qq][r0 + 1] = (ok1 != 0.f) ? s1 + b3v : NEG;
                sScore[qq][r0 + 2] = (ok2 != 0.f) ? s2 + b3v : NEG;
                sScore[qq][r0 + 3] = (ok3 != 0.f) ? s3 + b3v : NEG;
            }
        }
    }
    __syncthreads();

    // ---- paired softmax over 512 scores, 1 k per thread per q ----
    const float NEG = -__builtin_inff();
    float v[2], mr[2];
    #pragma unroll
    for (int qq = 0; qq < 2; ++qq) {
        v[qq] = (t < VL) ? sScore[qq][t] : NEG;
        mr[qq] = v[qq];
    }
    #pragma unroll
    for (int off = 32; off > 0; off >>= 1) {
        mr[0] = fmaxf(mr[0], __shfl_down(mr[0], off));
        mr[1] = fmaxf(mr[1], __shfl_down(mr[1], off));
    }
    if (lane == 0) { sRed[0][w] = mr[0]; sRed[1][w] = mr[1]; }
    __syncthreads();
    if (t == 0) {
        float m0 = sRed[0][0], m1 = sRed[1][0];
        #pragma unroll
        for (int i = 1; i < 8; ++i) {
            m0 = fmaxf(m0, sRed[0][i]);
            m1 = fmaxf(m1, sRed[1][i]);
        }
        sRed[0][8] = m0; sRed[1][8] = m1;
    }
    __syncthreads();

    const float L2E = 1.4426950408889634f;
    float e[2], sum[2];
    #pragma unroll
    for (int qq = 0; qq < 2; ++qq) {
        float mx = sRed[qq][8];
        int fin = (mx > -1e37f);
        e[qq] = (fin && v[qq] > -1e37f) ? __builtin_amdgcn_exp2f((v[qq] - mx) * L2E) : 0.f;
        sE[qq][t] = e[qq];
        sum[qq] = e[qq];
    }
    #pragma unroll
    for (int off = 32; off > 0; off >>= 1) {
        sum[0] += __shfl_down(sum[0], off);
        sum[1] += __shfl_down(sum[1], off);
    }
    if (lane == 0) { sRed[0][w] = sum[0]; sRed[1][w] = sum[1]; }
    __syncthreads();
    if (t == 0) {
        float s0 = 0.f, s1 = 0.f;
        #pragma unroll
        for (int i = 0; i < 8; ++i) { s0 += sRed[0][i]; s1 += sRed[1][i]; }
        sRed[0][8] = (s0 > 0.f) ? 1.f / s0 : 0.f;
        sRed[1][8] = (s1 > 0.f) ? 1.f / s1 : 0.f;
    }
    __syncthreads();
    float rinv[2] = { sRed[0][8], sRed[1][8] };

    int bf16m = (((const u32*)qs_t_src)[0] != 0x3F800000u);
    #pragma unroll
    for (int qq = 0; qq < 2; ++qq) {
        int oattn = B_ * Q_ * HV_ + (b * Q_ + q0 + qq) * K_ + t;
        if (bf16m) ((u16*)d_out)[oattn] = f2bf(e[qq] * rinv[qq]);
        else       ((float*)d_out)[oattn] = e[qq] * rinv[qq];
    }

    // ---- ctx for both q's; vproj loads shared; 8 k-groups of 64 ----
    int h = t & 63, ksp = t >> 6;
    const float* vp = vproj + b * K_ * HV_ + h;
    float a0 = 0.f, a1 = 0.f;
    int kbeg = ksp * 64;
    for (int kk = kbeg; kk < kbeg + 64; ++kk) {
        float vv = vp[kk * HV_];
        a0 = __builtin_fmaf(sE[0][kk], vv, a0);
        a1 = __builtin_fmaf(sE[1][kk], vv, a1);
    }
    sPart[0][ksp][h] = a0;
    sPart[1][ksp][h] = a1;
    __syncthreads();
    if (t < 128) {
        int qq = t >> 6, hh = t & 63;
        float c = 0.f;
        #pragma unroll
        for (int p = 0; p < 8; ++p) c += sPart[qq][p][hh];
        c *= rinv[qq];
        int octx = (b * Q_ + q0 + qq) * HV_ + hh;
        if (bf16m) ((u16*)d_out)[octx] = f2bf(c);
        else       ((float*)d_out)[octx] = c;
    }
}

extern "C" void kernel_launch(void* const* d_in, const int* in_sizes, int n_in,
                              void* d_out, int out_size, void* d_ws, size_t ws_size,
                              hipStream_t stream) {
    float* wsf = (float*)d_ws;

    convert_kernel<<<dim3(964), dim3(256), 0, stream>>>(
        d_in[0], d_in[1], d_in[2], d_in[3], d_in[4], d_in[5], d_in[6], d_in[7],
        d_in[8], d_in[9], d_in[10], d_in[11], d_in[12], d_in[13], d_in[14], d_in[15],
        d_in[16], wsf);

    prep_kernel<<<dim3(4608), dim3(256), 0, stream>>>(
        wsf + OFF_QS, wsf + OFF_KS, wsf + OFF_VS, wsf + OFF_VN,
        wsf + OFF_QSS, wsf + OFF_KSS, wsf + OFF_QST, wsf + OFF_KST,
        wsf + OFF_W1, wsf + OFF_B1, wsf + OFF_WV, wsf + OFF_BV,
        wsf + OFF_AQ, wsf + OFF_AK, wsf + OFF_VP);

    fused_kernel<<<dim3(Q_ / 2, B_), dim3(512), 0, stream>>>(
        wsf + OFF_QSS, wsf + OFF_KSS, wsf + OFF_QST, wsf + OFF_KST,
        wsf + OFF_W1, (const u32*)(wsf + OFF_W2), wsf + OFF_B2, wsf + OFF_W3, wsf + OFF_B3,
        (const int*)(wsf + OFF_VL), wsf + OFF_AQ, wsf + OFF_AK, wsf + OFF_VP,
        d_in[6], d_out);
}

// Round 10
// 84.288 us; speedup vs baseline: 1.6190x; 1.6190x over previous
//
#include <hip/hip_runtime.h>

#define B_ 4
#define Q_ 512
#define K_ 512
#define F_ 32
#define H1_ 256
#define H2_ 64
#define HV_ 64

typedef unsigned short u16;
typedef unsigned int u32;

typedef float f32x4 __attribute__((ext_vector_type(4)));
typedef short short8 __attribute__((ext_vector_type(8)));
typedef __bf16 bfv8 __attribute__((ext_vector_type(8)));
union FRG { short8 s; bfv8 h; u32 u[4]; };

// ---- workspace layout (float units from ws base) ----
#define OFF_QS   0
#define OFF_KS   65536
#define OFF_VS   131072
#define OFF_VN   196608
#define OFF_QSS  196736
#define OFF_KSS  200832
#define OFF_QST  204928
#define OFF_KST  206976
#define OFF_W1   209024
#define OFF_B1   234880
#define OFF_W2   235136   /* u32 region: 8192 u32 packed B-fragments */
#define OFF_B2   243328
#define OFF_W3   243392
#define OFF_B3   243456
#define OFF_WV   243460
#define OFF_BV   245508
#define OFF_VL   245572   /* 4 ints */
#define OFF_AQ   262144
#define OFF_AK   786432   /* row-major Ak[b][k][d], 524288 floats */
#define OFF_VP   1310720

__device__ __forceinline__ float bf2f(u16 u) {
    union { u32 u; float f; } c; c.u = ((u32)u) << 16; return c.f;
}
__device__ __forceinline__ u16 f2bf(float f) {
    union { float f; u32 u; } c; c.f = f;
    u32 u = c.u;
    return (u16)((u + 0x7FFFu + ((u >> 16) & 1u)) >> 16);
}
// jax.nn.gelu(approximate=True) == x - x/(1+exp2(x*(K + Kc*x^2)))
__device__ __forceinline__ float gelu_t(float x) {
    const float Kb = 2.3022082f;     // 2*sqrt(2/pi)*log2(e)
    const float Kc = 0.10294324f;    // Kb*0.044715
    float y = x * __builtin_fmaf(Kc, x * x, Kb);
    float e = __builtin_amdgcn_exp2f(y);
    return x - x * __builtin_amdgcn_rcpf(e + 1.0f);  // exact at both tails
}

// ---------------- convert: canonicalize inputs to f32; pack W2 into MFMA B-fragments --------
__global__ __launch_bounds__(256) void convert_kernel(
    const void* s0, const void* s1, const void* s2, const void* s3,
    const void* s4, const void* s5, const void* s6, const void* s7,
    const void* s8, const void* s9, const void* s10, const void* s11,
    const void* s12, const void* s13, const void* s14, const void* s15,
    const void* s16, float* wsf)
{
    int blk = blockIdx.x, t = threadIdx.x;
    // qs_t is all ones: f32 -> 0x3F800000, bf16 pair -> 0x3F803F80
    int bf16m = (((const u32*)s6)[0] != 0x3F800000u);

    if (blk == 963) {           // valid_lens (int32 or int64 hedge)
        if (t < 4) {
            const int* vi = (const int*)s16;
            int is64 = (vi[1] == 0);
            ((int*)(wsf + OFF_VL))[t] = vi[is64 ? 2 * t : t];
        }
        return;
    }
    if (blk >= 919 && blk < 951) {   // W2 -> packed B-fragments W2F[ks][n][lane][r]
        int idx = (blk - 919) * 256 + t;           // 0..8191
        int r  = idx & 3;
        int l  = (idx >> 2) & 63;
        int n  = (idx >> 8) & 3;
        int ks = idx >> 10;
        int k0  = ks * 32 + (l >> 4) * 8 + 2 * r;
        int col = n * 16 + (l & 15);
        u16 lo, hi;
        if (bf16m) {
            lo = ((const u16*)s10)[k0 * H2_ + col];
            hi = ((const u16*)s10)[(k0 + 1) * H2_ + col];
        } else {
            lo = f2bf(((const float*)s10)[k0 * H2_ + col]);
            hi = f2bf(((const float*)s10)[(k0 + 1) * H2_ + col]);
        }
        ((u32*)(wsf + OFF_W2))[idx] = (u32)lo | ((u32)hi << 16);
        return;
    }
    const void* src; int n, dst, b0;
    if      (blk < 256) { src = s0;  n = 65536; dst = OFF_QS;  b0 = 0;   }
    else if (blk < 512) { src = s1;  n = 65536; dst = OFF_KS;  b0 = 256; }
    else if (blk < 768) { src = s2;  n = 65536; dst = OFF_VS;  b0 = 512; }
    else if (blk < 769) { src = s3;  n = 128;   dst = OFF_VN;  b0 = 768; }
    else if (blk < 785) { src = s4;  n = 4096;  dst = OFF_QSS; b0 = 769; }
    else if (blk < 801) { src = s5;  n = 4096;  dst = OFF_KSS; b0 = 785; }
    else if (blk < 809) { src = s6;  n = 2048;  dst = OFF_QST; b0 = 801; }
    else if (blk < 817) { src = s7;  n = 2048;  dst = OFF_KST; b0 = 809; }
    else if (blk < 918) { src = s8;  n = 25856; dst = OFF_W1;  b0 = 817; }
    else if (blk < 919) { src = s9;  n = 256;   dst = OFF_B1;  b0 = 918; }
    else if (blk < 952) { src = s11; n = 64;    dst = OFF_B2;  b0 = 951; }
    else if (blk < 953) { src = s12; n = 64;    dst = OFF_W3;  b0 = 952; }
    else if (blk < 954) { src = s13; n = 1;     dst = OFF_B3;  b0 = 953; }
    else if (blk < 962) { src = s14; n = 2048;  dst = OFF_WV;  b0 = 954; }
    else                { src = s15; n = 64;    dst = OFF_BV;  b0 = 962; }
    int idx = (blk - b0) * 256 + t;
    if (idx < n)
        (wsf + dst)[idx] = bf16m ? bf2f(((const u16*)src)[idx]) : ((const float*)src)[idx];
}

// ---------------- prep: Aq, Ak (row-major), vproj — all f32 ----------------
__global__ __launch_bounds__(256) void prep_kernel(
    const float* __restrict__ qs, const float* __restrict__ ks, const float* __restrict__ vs,
    const float* __restrict__ vnode, const float* __restrict__ qs_s, const float* __restrict__ ks_s,
    const float* __restrict__ qs_t, const float* __restrict__ ks_t,
    const float* __restrict__ W1, const float* __restrict__ b1,
    const float* __restrict__ Wv, const float* __restrict__ bv,
    float* __restrict__ Aq, float* __restrict__ Ak, float* __restrict__ vproj)
{
    int blk = blockIdx.x;
    int t = threadIdx.x;
    if (blk < 2048) {                       // Aq row per (b,q)
        int b = blk >> 9, q = blk & 511, d = t;
        float acc = b1[d];
        const float* qrow = qs + (b * Q_ + q) * F_;
        #pragma unroll
        for (int f = 0; f < F_; ++f)
            acc = __builtin_fmaf(qrow[f], W1[f * H1_ + d], acc);
        const float* vn = vnode + b * 32;
        #pragma unroll
        for (int f = 0; f < 32; ++f)
            acc = __builtin_fmaf(vn[f], W1[(64 + f) * H1_ + d], acc);
        float q0 = qs_s[(b * Q_ + q) * 2 + 0];
        float q1 = qs_s[(b * Q_ + q) * 2 + 1];
        float qt = qs_t[b * Q_ + q];
        acc = __builtin_fmaf(q0, W1[96 * H1_ + d], acc);
        acc = __builtin_fmaf(q1, W1[97 * H1_ + d], acc);
        acc = __builtin_fmaf(qt, W1[100 * H1_ + d], acc);
        Aq[blk * H1_ + d] = acc;
    } else if (blk < 4096) {                // Ak[b][k][d]
        int rk = blk - 2048;
        int b = rk >> 9, k = rk & 511, d = t;
        float acc = 0.f;
        const float* krow = ks + (b * K_ + k) * F_;
        #pragma unroll
        for (int f = 0; f < F_; ++f)
            acc = __builtin_fmaf(krow[f], W1[(32 + f) * H1_ + d], acc);
        float k0 = ks_s[(b * K_ + k) * 2 + 0];
        float k1 = ks_s[(b * K_ + k) * 2 + 1];
        float kt = ks_t[b * K_ + k];
        acc = __builtin_fmaf(-k0, W1[96 * H1_ + d], acc);
        acc = __builtin_fmaf(-k1, W1[97 * H1_ + d], acc);
        acc = __builtin_fmaf(-kt, W1[100 * H1_ + d], acc);
        Ak[(b * K_ + k) * H1_ + d] = acc;   // row-major: lane reads 8 consecutive d
    } else {                                // vproj[(b,k),h]
        int idx = (blk - 4096) * 256 + t;
        int h = idx & 63;
        int k = (idx >> 6) & 511;
        int b = idx >> 15;
        float acc = bv[h];
        const float* vrow = vs + (b * K_ + k) * F_;
        #pragma unroll
        for (int f = 0; f < F_; ++f)
            acc = __builtin_fmaf(vrow[f], Wv[f * HV_ + h], acc);
        vproj[idx] = acc;
    }
}

// ---------------- fused: 2 q's per 8-wave block; MFMA MLP + softmax + attn + ctx ------
// Waves stride 16-row tiles by 8; Ak/W2F/vproj loads amortized across the q-pair.
// launch_bounds min-waves=4 (NOT 8): 8 forced VGPR=32 -> spill storm (r9: FETCH 85MB).
__global__ __launch_bounds__(512, 4) void fused_kernel(
    const float* __restrict__ qs_s, const float* __restrict__ ks_s,
    const float* __restrict__ qs_t, const float* __restrict__ ks_t,
    const float* __restrict__ W1, const u32* __restrict__ W2F,
    const float* __restrict__ b2, const float* __restrict__ W3, const float* __restrict__ b3,
    const int* __restrict__ vl, const float* __restrict__ Aq, const float* __restrict__ Ak,
    const float* __restrict__ vproj, const void* __restrict__ qs_t_src, void* __restrict__ d_out)
{
    __shared__ __align__(16) float sAq[2][H1_];
    __shared__ __align__(16) float sw98[H1_], sw99[H1_];
    __shared__ float sScore[2][K_];
    __shared__ float sE[2][K_];
    __shared__ float sRed[2][12];
    __shared__ float sPart[2][8][HV_];

    int q0 = blockIdx.x * 2, b = blockIdx.y, t = threadIdx.x;
    int lane = t & 63, w = t >> 6;         // 8 waves
    int VL = vl[b];
    int nT = (VL + 15) >> 4;               // m-tiles of 16 rows covering [0, VL)

    if (t < H1_) {
        sAq[0][t] = Aq[(b * Q_ + q0) * H1_ + t];
        sAq[1][t] = Aq[(b * Q_ + q0 + 1) * H1_ + t];
        sw98[t] = W1[98 * H1_ + t];
        sw99[t] = W1[99 * H1_ + t];
    }
    __syncthreads();

    float qx0[2], qx1[2], qtv[2];
    #pragma unroll
    for (int qq = 0; qq < 2; ++qq) {
        qx0[qq] = qs_s[(b * Q_ + q0 + qq) * 2 + 0];
        qx1[qq] = qs_s[(b * Q_ + q0 + qq) * 2 + 1];
        qtv[qq] = qs_t[b * Q_ + q0 + qq];
    }

    float b2c[4], w3c[4];
    #pragma unroll
    for (int n = 0; n < 4; ++n) {
        int col = n * 16 + (lane & 15);
        b2c[n] = b2[col];
        w3c[n] = W3[col];
    }
    float b3v = b3[0];
    const float* Ak_b = Ak + (size_t)b * K_ * H1_;
    int lgrp = (lane >> 4) * 8;

    for (int tile = w; tile < nT; tile += 8) {     // wave-uniform strided tiles
        int row = tile * 16 + (lane & 15);
        float c0 = ks_s[(b * K_ + row) * 2 + 0];
        float c1 = ks_s[(b * K_ + row) * 2 + 1];
        float ktv = ks_t[b * K_ + row];
        float dsq[2], dist[2], okf[2];
        #pragma unroll
        for (int qq = 0; qq < 2; ++qq) {
            float d0 = qx0[qq] - c0, d1 = qx1[qq] - c1;
            dsq[qq]  = __builtin_fmaf(d0, d0, d1 * d1);
            dist[qq] = sqrtf(dsq[qq]);
            okf[qq] = (row < VL && (qtv[qq] - ktv) >= 0.f && dist[qq] <= 1e30f) ? 1.f : 0.f;
        }

        f32x4 acc[2][4];
        #pragma unroll
        for (int qq = 0; qq < 2; ++qq)
            #pragma unroll
            for (int n = 0; n < 4; ++n) acc[qq][n] = (f32x4){0.f, 0.f, 0.f, 0.f};

        const float* akrow = Ak_b + row * H1_;
        #pragma unroll 2
        for (int ks = 0; ks < 8; ++ks) {
            int dbase = ks * 32 + lgrp;
            f32x4 w98a = *(const f32x4*)&sw98[dbase];
            f32x4 w98b = *(const f32x4*)&sw98[dbase + 4];
            f32x4 w99a = *(const f32x4*)&sw99[dbase];
            f32x4 w99b = *(const f32x4*)&sw99[dbase + 4];
            f32x4 ak0 = *(const f32x4*)(akrow + dbase);
            f32x4 ak1 = *(const f32x4*)(akrow + dbase + 4);
            short8 bf[4];
            #pragma unroll
            for (int n = 0; n < 4; ++n)
                bf[n] = *(const short8*)&W2F[((ks * 4 + n) * 64 + lane) * 4];  // L1-hot
            FRG fa[2];
            #pragma unroll
            for (int qq = 0; qq < 2; ++qq) {
                f32x4 aqa = *(const f32x4*)&sAq[qq][dbase];
                f32x4 aqb = *(const f32x4*)&sAq[qq][dbase + 4];
                #pragma unroll
                for (int j = 0; j < 4; ++j) {
                    float pre = ak0[j] + __builtin_fmaf(dist[qq], w98a[j],
                               __builtin_fmaf(dsq[qq], w99a[j], aqa[j]));
                    fa[qq].h[j] = (__bf16)gelu_t(pre);
                }
                #pragma unroll
                for (int j = 0; j < 4; ++j) {
                    float pre = ak1[j] + __builtin_fmaf(dist[qq], w98b[j],
                               __builtin_fmaf(dsq[qq], w99b[j], aqb[j]));
                    fa[qq].h[4 + j] = (__bf16)gelu_t(pre);
                }
            }
            #pragma unroll
            for (int n = 0; n < 4; ++n) {
                acc[0][n] = __builtin_amdgcn_mfma_f32_16x16x32_bf16(fa[0].s, bf[n], acc[0][n], 0, 0, 0);
                acc[1][n] = __builtin_amdgcn_mfma_f32_16x16x32_bf16(fa[1].s, bf[n], acc[1][n], 0, 0, 0);
            }
        }

        // ---- layer-3 for this tile, both q's ----
        #pragma unroll
        for (int qq = 0; qq < 2; ++qq) {
            float s0 = 0.f, s1 = 0.f, s2 = 0.f, s3 = 0.f;
            #pragma unroll
            for (int n = 0; n < 4; ++n) {
                f32x4 a = acc[qq][n];
                s0 = __builtin_fmaf(gelu_t(a.x + b2c[n]), w3c[n], s0);
                s1 = __builtin_fmaf(gelu_t(a.y + b2c[n]), w3c[n], s1);
                s2 = __builtin_fmaf(gelu_t(a.z + b2c[n]), w3c[n], s2);
                s3 = __builtin_fmaf(gelu_t(a.w + b2c[n]), w3c[n], s3);
            }
            #pragma unroll
            for (int off = 1; off < 16; off <<= 1) {
                s0 += __shfl_xor(s0, off);
                s1 += __shfl_xor(s1, off);
                s2 += __shfl_xor(s2, off);
                s3 += __shfl_xor(s3, off);
            }
            int g = lane >> 4;
            float ok0 = __shfl(okf[qq], g * 4 + 0);
            float ok1 = __shfl(okf[qq], g * 4 + 1);
            float ok2 = __shfl(okf[qq], g * 4 + 2);
            float ok3 = __shfl(okf[qq], g * 4 + 3);
            if ((lane & 15) == 0) {
                int r0 = tile * 16 + g * 4;
                const float NEG = -__builtin_inff();
                sScore[qq][r0 + 0] = (ok0 != 0.f) ? s0 + b3v : NEG;
                sScore[qq][r0 + 1] = (ok1 != 0.f) ? s1 + b3v : NEG;
                sScore[qq][r0 + 2] = (ok2 != 0.f) ? s2 + b3v : NEG;
                sScore[qq][r0 + 3] = (ok3 != 0.f) ? s3 + b3v : NEG;
            }
        }
    }
    __syncthreads();

    // ---- paired softmax over 512 scores, 1 k per thread per q ----
    const float NEG = -__builtin_inff();
    float v[2], mr[2];
    #pragma unroll
    for (int qq = 0; qq < 2; ++qq) {
        v[qq] = (t < VL) ? sScore[qq][t] : NEG;
        mr[qq] = v[qq];
    }
    #pragma unroll
    for (int off = 32; off > 0; off >>= 1) {
        mr[0] = fmaxf(mr[0], __shfl_down(mr[0], off));
        mr[1] = fmaxf(mr[1], __shfl_down(mr[1], off));
    }
    if (lane == 0) { sRed[0][w] = mr[0]; sRed[1][w] = mr[1]; }
    __syncthreads();
    if (t == 0) {
        float m0 = sRed[0][0], m1 = sRed[1][0];
        #pragma unroll
        for (int i = 1; i < 8; ++i) {
            m0 = fmaxf(m0, sRed[0][i]);
            m1 = fmaxf(m1, sRed[1][i]);
        }
        sRed[0][8] = m0; sRed[1][8] = m1;
    }
    __syncthreads();

    const float L2E = 1.4426950408889634f;
    float e[2], sum[2];
    #pragma unroll
    for (int qq = 0; qq < 2; ++qq) {
        float mx = sRed[qq][8];
        int fin = (mx > -1e37f);
        e[qq] = (fin && v[qq] > -1e37f) ? __builtin_amdgcn_exp2f((v[qq] - mx) * L2E) : 0.f;
        sE[qq][t] = e[qq];
        sum[qq] = e[qq];
    }
    #pragma unroll
    for (int off = 32; off > 0; off >>= 1) {
        sum[0] += __shfl_down(sum[0], off);
        sum[1] += __shfl_down(sum[1], off);
    }
    if (lane == 0) { sRed[0][w] = sum[0]; sRed[1][w] = sum[1]; }
    __syncthreads();
    if (t == 0) {
        float s0 = 0.f, s1 = 0.f;
        #pragma unroll
        for (int i = 0; i < 8; ++i) { s0 += sRed[0][i]; s1 += sRed[1][i]; }
        sRed[0][8] = (s0 > 0.f) ? 1.f / s0 : 0.f;
        sRed[1][8] = (s1 > 0.f) ? 1.f / s1 : 0.f;
    }
    __syncthreads();
    float rinv[2] = { sRed[0][8], sRed[1][8] };

    int bf16m = (((const u32*)qs_t_src)[0] != 0x3F800000u);
    #pragma unroll
    for (int qq = 0; qq < 2; ++qq) {
        int oattn = B_ * Q_ * HV_ + (b * Q_ + q0 + qq) * K_ + t;
        if (bf16m) ((u16*)d_out)[oattn] = f2bf(e[qq] * rinv[qq]);
        else       ((float*)d_out)[oattn] = e[qq] * rinv[qq];
    }

    // ---- ctx for both q's; vproj loads shared; 8 k-groups of 64 ----
    int h = t & 63, ksp = t >> 6;
    const float* vp = vproj + b * K_ * HV_ + h;
    float a0 = 0.f, a1 = 0.f;
    int kbeg = ksp * 64;
    for (int kk = kbeg; kk < kbeg + 64; ++kk) {
        float vv = vp[kk * HV_];
        a0 = __builtin_fmaf(sE[0][kk], vv, a0);
        a1 = __builtin_fmaf(sE[1][kk], vv, a1);
    }
    sPart[0][ksp][h] = a0;
    sPart[1][ksp][h] = a1;
    __syncthreads();
    if (t < 128) {
        int qq = t >> 6, hh = t & 63;
        float c = 0.f;
        #pragma unroll
        for (int p = 0; p < 8; ++p) c += sPart[qq][p][hh];
        c *= rinv[qq];
        int octx = (b * Q_ + q0 + qq) * HV_ + hh;
        if (bf16m) ((u16*)d_out)[octx] = f2bf(c);
        else       ((float*)d_out)[octx] = c;
    }
}

extern "C" void kernel_launch(void* const* d_in, const int* in_sizes, int n_in,
                              void* d_out, int out_size, void* d_ws, size_t ws_size,
                              hipStream_t stream) {
    float* wsf = (float*)d_ws;

    convert_kernel<<<dim3(964), dim3(256), 0, stream>>>(
        d_in[0], d_in[1], d_in[2], d_in[3], d_in[4], d_in[5], d_in[6], d_in[7],
        d_in[8], d_in[9], d_in[10], d_in[11], d_in[12], d_in[13], d_in[14], d_in[15],
        d_in[16], wsf);

    prep_kernel<<<dim3(4608), dim3(256), 0, stream>>>(
        wsf + OFF_QS, wsf + OFF_KS, wsf + OFF_VS, wsf + OFF_VN,
        wsf + OFF_QSS, wsf + OFF_KSS, wsf + OFF_QST, wsf + OFF_KST,
        wsf + OFF_W1, wsf + OFF_B1, wsf + OFF_WV, wsf + OFF_BV,
        wsf + OFF_AQ, wsf + OFF_AK, wsf + OFF_VP);

    fused_kernel<<<dim3(Q_ / 2, B_), dim3(512), 0, stream>>>(
        wsf + OFF_QSS, wsf + OFF_KSS, wsf + OFF_QST, wsf + OFF_KST,
        wsf + OFF_W1, (const u32*)(wsf + OFF_W2), wsf + OFF_B2, wsf + OFF_W3, wsf + OFF_B3,
        (const int*)(wsf + OFF_VL), wsf + OFF_AQ, wsf + OFF_AK, wsf + OFF_VP,
        d_in[6], d_out);
}